// Round 5
// baseline (463.242 us; speedup 1.0000x reference)
//
#include <hip/hip_runtime.h>
#include <hip/hip_bf16.h>
#include <math.h>

#define NUM_USERS 60000
#define NUM_ITEMS 40000
#define NUM_NODES (NUM_USERS + NUM_ITEMS)
#define NNZ 2000000
#define DIM 64
#define BATCH 4096
#define TEMP_INV 5.0f   // 1/0.2
#define SCAN_BLOCKS ((NUM_NODES + 1023) / 1024)   // 98
#define PAIR_CAP (NNZ + NUM_NODES * 8)

#define HIST_BLOCKS 1954      // 500000 int4 groups / 256
#define CVT_BLOCKS 1563       // 400000 float4 groups / 256

typedef __attribute__((ext_vector_type(8))) __bf16 bf16x8;
typedef __attribute__((ext_vector_type(4))) float f32x4;

__device__ __forceinline__ ushort f2bf(float f) {           // RNE, finite inputs
    uint u = __float_as_uint(f);
    return (ushort)((u + 0x7FFF + ((u >> 16) & 1)) >> 16);
}
__device__ __forceinline__ float bf2f(ushort u) {
    return __uint_as_float((uint)u << 16);
}

// ---------------- fused: edge-row histogram (fire-and-forget) + table cvt ----

__global__ __launch_bounds__(256) void fused1_kernel(const int* __restrict__ row,
        int* __restrict__ cnt, const float* __restrict__ ut,
        const float* __restrict__ it, ushort* __restrict__ x0) {
    int b = blockIdx.x;
    if (b < HIST_BLOCKS) {
        int g = b * 256 + threadIdx.x;
        if (g < NNZ / 4) {
            int4 r = ((const int4*)row)[g];
            atomicAdd(&cnt[r.x], 1);
            atomicAdd(&cnt[r.y], 1);
            atomicAdd(&cnt[r.z], 1);
            atomicAdd(&cnt[r.w], 1);
        }
    } else {
        int g = (b - HIST_BLOCKS) * 256 + threadIdx.x;
        const int total4 = NUM_NODES * DIM / 4;
        if (g < total4) {
            size_t off = (size_t)g * 4;
            const float* src = (off < (size_t)NUM_USERS * DIM)
                                   ? ut + off
                                   : it + (off - (size_t)NUM_USERS * DIM);
            float4 v = *(const float4*)src;
            ushort4 o;
            o.x = f2bf(v.x); o.y = f2bf(v.y); o.z = f2bf(v.z); o.w = f2bf(v.w);
            *(ushort4*)&x0[off] = o;
        }
    }
}

// ---------------- CSR scan (rows padded to multiple of 8) ----------------

__global__ __launch_bounds__(1024) void scan1_kernel(const int* __restrict__ cnt,
        int* __restrict__ ptr, int* __restrict__ bsum, int n) {
    __shared__ int sh[1024];
    int t = threadIdx.x;
    int i = blockIdx.x * 1024 + t;
    int v = (i < n) ? ((cnt[i] + 7) & ~7) : 0;   // padded row length
    sh[t] = v;
    __syncthreads();
    for (int d = 1; d < 1024; d <<= 1) {
        int w = (t >= d) ? sh[t - d] : 0;
        __syncthreads();
        sh[t] += w;
        __syncthreads();
    }
    int incl = sh[t];
    if (i < n) ptr[i] = incl - v;
    if (t == 1023) bsum[blockIdx.x] = incl;
}

__global__ __launch_bounds__(128) void scan2_kernel(const int* __restrict__ bsum,
        int* __restrict__ boffs, int* __restrict__ ptr, int nb, int n) {
    __shared__ int sh[128];
    int t = threadIdx.x;
    int v = (t < nb) ? bsum[t] : 0;
    sh[t] = v;
    __syncthreads();
    for (int d = 1; d < 128; d <<= 1) {
        int w = (t >= d) ? sh[t - d] : 0;
        __syncthreads();
        sh[t] += w;
        __syncthreads();
    }
    if (t < nb) boffs[t] = sh[t] - v;
    if (t == 127) ptr[n] = sh[127];
}

__global__ __launch_bounds__(1024) void scan3_kernel(int* __restrict__ ptr,
        int* __restrict__ cur, const int* __restrict__ boffs, int n) {
    int i = blockIdx.x * 1024 + threadIdx.x;
    if (i < n) {
        int p = ptr[i] + boffs[blockIdx.x];
        ptr[i] = p;
        cur[i] = p;      // scatter cursor starts at row base
    }
}

// ---------------- scatter with atomic cursor (4 edges/thread) ----------------

__global__ __launch_bounds__(256) void scatter_kernel(const int* __restrict__ row,
        const int* __restrict__ col, const float* __restrict__ val,
        int* __restrict__ cur, int2* __restrict__ pairs) {
    int g = blockIdx.x * 256 + threadIdx.x;
    if (g >= NNZ / 4) return;
    int4 r = ((const int4*)row)[g];
    int4 c = ((const int4*)col)[g];
    float4 v = ((const float4*)val)[g];
    int p0 = atomicAdd(&cur[r.x], 1);
    int p1 = atomicAdd(&cur[r.y], 1);
    int p2 = atomicAdd(&cur[r.z], 1);
    int p3 = atomicAdd(&cur[r.w], 1);
    pairs[p0] = make_int2(c.x, __float_as_int(v.x));
    pairs[p1] = make_int2(c.y, __float_as_int(v.y));
    pairs[p2] = make_int2(c.z, __float_as_int(v.z));
    pairs[p3] = make_int2(c.w, __float_as_int(v.w));
}

// ---------------- SpMM: wave per row, lane per dim, bf16 in/out ----------------
// Row length is a multiple of 8; pad slots are (col=0, val=0) from the memset.

__global__ __launch_bounds__(256) void spmm_kernel(const ushort* __restrict__ xin,
        ushort* __restrict__ xout,
        const int* __restrict__ ptr, const int2* __restrict__ pairs) {
    int wid = (blockIdx.x * 256 + threadIdx.x) >> 6;
    int lane = threadIdx.x & 63;
    if (wid >= NUM_NODES) return;
    int s = ptr[wid], e = ptr[wid + 1];
    float a0 = 0.f, a1 = 0.f;
    if (s < e) {
        int2 p = pairs[s + (lane & 7)];          // prefetch first chunk
        for (int j = s; j < e; ) {
            int2 q = p;
            j += 8;
            if (j < e) p = pairs[j + (lane & 7)];  // prefetch next chunk
            #pragma unroll
            for (int k = 0; k < 8; ++k) {
                int c = __shfl(q.x, k);
                float v = __int_as_float(__shfl(q.y, k));
                float xv = bf2f(xin[c * DIM + lane]);
                if (k & 1) a1 = fmaf(v, xv, a1); else a0 = fmaf(v, xv, a0);
            }
        }
    }
    xout[wid * DIM + lane] = f2bf(a0 + a1);
}

// ---------------- fused BPR + reg + normalize (wave per batch elem) ----------

__device__ __forceinline__ float wave_sum(float v) {
    for (int o = 32; o; o >>= 1) v += __shfl_xor(v, o);
    return v;
}

__device__ __forceinline__ float acc3(const ushort* x1, const ushort* x2,
                                      const ushort* x3, int node, int lane) {
    int o = node * DIM + lane;
    return (bf2f(x1[o]) + bf2f(x2[o]) + bf2f(x3[o])) * (1.f / 3.f);
}

__global__ __launch_bounds__(256) void loss_fused_kernel(const ushort* __restrict__ x1,
        const ushort* __restrict__ x2, const ushort* __restrict__ x3,
        const float* __restrict__ ut, const float* __restrict__ it,
        const int* __restrict__ user, const int* __restrict__ pos,
        const int* __restrict__ neg, ushort* __restrict__ vnh,
        float* __restrict__ posv, float* __restrict__ oacc) {
    int lane = threadIdx.x & 63;
    int wib = threadIdx.x >> 6;
    int b = blockIdx.x * 4 + wib;      // 1024 blocks x 4 waves = 4096
    int iu = user[b], ip = pos[b], in_ = neg[b];
    float u = acc3(x1, x2, x3, iu, lane);
    float p = acc3(x1, x2, x3, NUM_USERS + ip, lane);
    float n = acc3(x1, x2, x3, NUM_USERS + in_, lane);
    float dp = wave_sum(u * p);
    float dn = wave_sum(u * n);
    float x = dn - dp;
    float sp = fmaxf(x, 0.f) + log1pf(expf(-fabsf(x)));
    float eu = ut[(size_t)iu * DIM + lane];
    float ep = it[(size_t)ip * DIM + lane];
    float en = it[(size_t)in_ * DIM + lane];
    float r = wave_sum(eu * eu + ep * ep + en * en);
    // normalize u -> vnh[b], p -> vnh[BATCH+b]
    float un2 = wave_sum(u * u);
    float uinv = 1.f / (sqrtf(un2) + 1e-8f);
    vnh[b * DIM + lane] = f2bf(u * uinv);
    float pn2 = wave_sum(p * p);
    float pinv = 1.f / (sqrtf(pn2) + 1e-8f);
    vnh[(BATCH + b) * DIM + lane] = f2bf(p * pinv);
    __shared__ float lsp[4], lrg[4];
    if (lane == 0) {
        lsp[wib] = sp;
        lrg[wib] = r;
        posv[b] = un2 * uinv * uinv * TEMP_INV;
        posv[BATCH + b] = pn2 * pinv * pinv * TEMP_INV;
    }
    __syncthreads();
    if (threadIdx.x == 0) {
        atomicAdd(&oacc[0], lsp[0] + lsp[1] + lsp[2] + lsp[3]);
        atomicAdd(&oacc[1], lrg[0] + lrg[1] + lrg[2] + lrg[3]);
    }
}

// ---------------- MFMA gram + fixed-shift sumexp ----------------

__global__ __launch_bounds__(256) void gram2_kernel(const ushort* __restrict__ vnh_,
                                                    float* __restrict__ rowsum) {
    const __bf16* vnh = (const __bf16*)vnh_;
    int b = blockIdx.x;
    int side = b >> 10;
    int itile = (b >> 2) & 255;
    int jgroup = b & 3;
    int wave = threadIdx.x >> 6;
    int lane = threadIdx.x & 63;
    int jsub = jgroup * 4 + wave;            // 0..15
    const __bf16* base = vnh + (size_t)side * BATCH * DIM;
    int i0 = itile * 16;
    int row = lane & 15;
    int koff = (lane >> 4) * 8;
    bf16x8 a0 = *(const bf16x8*)&base[(i0 + row) * DIM + koff];
    bf16x8 a1 = *(const bf16x8*)&base[(i0 + row) * DIM + 32 + koff];
    float rs[4] = {0.f, 0.f, 0.f, 0.f};
    for (int t = 0; t < 16; ++t) {
        int j0 = (jsub + t * 16) * 16;
        bf16x8 b0 = *(const bf16x8*)&base[(j0 + row) * DIM + koff];
        bf16x8 b1 = *(const bf16x8*)&base[(j0 + row) * DIM + 32 + koff];
        f32x4 c = {0.f, 0.f, 0.f, 0.f};
        c = __builtin_amdgcn_mfma_f32_16x16x32_bf16(a0, b0, c, 0, 0, 0);
        c = __builtin_amdgcn_mfma_f32_16x16x32_bf16(a1, b1, c, 0, 0, 0);
        #pragma unroll
        for (int r = 0; r < 4; ++r)
            rs[r] += __expf(TEMP_INV * c[r] - TEMP_INV);   // logit-5 <= 0
    }
    #pragma unroll
    for (int r = 0; r < 4; ++r) {
        rs[r] += __shfl_xor(rs[r], 1);
        rs[r] += __shfl_xor(rs[r], 2);
        rs[r] += __shfl_xor(rs[r], 4);
        rs[r] += __shfl_xor(rs[r], 8);
    }
    if ((lane & 15) == 0) {
        #pragma unroll
        for (int r = 0; r < 4; ++r)
            atomicAdd(&rowsum[side * BATCH + i0 + (lane >> 4) * 4 + r], rs[r]);
    }
}

__global__ __launch_bounds__(256) void lse_kernel(const float* __restrict__ rowsum,
        const float* __restrict__ posv, float* __restrict__ oacc) {
    int idx = blockIdx.x * 256 + threadIdx.x;
    float c = 0.f;
    if (idx < 2 * BATCH) {
        float s = rowsum[idx];
        c = TEMP_INV + logf(s) - posv[idx];
    }
    c = wave_sum(c);
    __shared__ float l[4];
    int lane = threadIdx.x & 63, w = threadIdx.x >> 6;
    if (lane == 0) l[w] = c;
    __syncthreads();
    if (threadIdx.x == 0) atomicAdd(&oacc[2], l[0] + l[1] + l[2] + l[3]);
}

__global__ void final_kernel(const float* __restrict__ oacc, float* __restrict__ out) {
    out[0] = oacc[0] * (1.f / BATCH);
    out[1] = oacc[1] * (1e-4f * 0.5f / BATCH);
    out[2] = oacc[2] * (0.1f / BATCH);
}

// ---------------- launch ----------------

extern "C" void kernel_launch(void* const* d_in, const int* in_sizes, int n_in,
                              void* d_out, int out_size, void* d_ws, size_t ws_size,
                              hipStream_t stream) {
    const float* user_table = (const float*)d_in[0];
    const float* item_table = (const float*)d_in[1];
    const float* edge_val   = (const float*)d_in[2];
    const int*   user       = (const int*)d_in[3];
    const int*   positive   = (const int*)d_in[4];
    const int*   negative   = (const int*)d_in[5];
    const int*   edge_row   = (const int*)d_in[6];
    const int*   edge_col   = (const int*)d_in[7];
    float* out = (float*)d_out;

    char* w = (char*)d_ws;
    auto alloc = [&](size_t bytes) {
        char* p = w;
        w += (bytes + 255) & ~(size_t)255;
        return p;
    };
    int*    row_ptr = (int*)alloc((NUM_NODES + 1) * sizeof(int));
    int*    cnt     = (int*)alloc(NUM_NODES * sizeof(int));
    int*    cur     = (int*)alloc(NUM_NODES * sizeof(int));
    int*    bsum    = (int*)alloc(SCAN_BLOCKS * sizeof(int));
    int*    boffs   = (int*)alloc(SCAN_BLOCKS * sizeof(int));
    int2*   pairs   = (int2*)alloc((size_t)PAIR_CAP * sizeof(int2));
    ushort* x0h     = (ushort*)alloc((size_t)NUM_NODES * DIM * sizeof(ushort));
    ushort* x1h     = (ushort*)alloc((size_t)NUM_NODES * DIM * sizeof(ushort));
    ushort* x2h     = (ushort*)alloc((size_t)NUM_NODES * DIM * sizeof(ushort));
    ushort* x3h     = (ushort*)alloc((size_t)NUM_NODES * DIM * sizeof(ushort));
    ushort* vnh     = (ushort*)alloc((size_t)2 * BATCH * DIM * sizeof(ushort));
    float*  posv    = (float*)alloc(2 * BATCH * sizeof(float));
    float*  rowsum  = (float*)alloc(2 * BATCH * sizeof(float));
    float*  oacc    = (float*)alloc(4 * sizeof(float));

    hipMemsetAsync(cnt, 0, NUM_NODES * sizeof(int), stream);
    hipMemsetAsync(oacc, 0, 4 * sizeof(float), stream);
    hipMemsetAsync(rowsum, 0, 2 * BATCH * sizeof(float), stream);
    hipMemsetAsync(pairs, 0, (size_t)PAIR_CAP * sizeof(int2), stream);

    fused1_kernel<<<HIST_BLOCKS + CVT_BLOCKS, 256, 0, stream>>>(
        edge_row, cnt, user_table, item_table, x0h);
    scan1_kernel<<<SCAN_BLOCKS, 1024, 0, stream>>>(cnt, row_ptr, bsum, NUM_NODES);
    scan2_kernel<<<1, 128, 0, stream>>>(bsum, boffs, row_ptr, SCAN_BLOCKS, NUM_NODES);
    scan3_kernel<<<SCAN_BLOCKS, 1024, 0, stream>>>(row_ptr, cur, boffs, NUM_NODES);
    scatter_kernel<<<(NNZ / 4 + 255) / 256, 256, 0, stream>>>(
        edge_row, edge_col, edge_val, cur, pairs);

    const int SPMM_BLOCKS = (NUM_NODES + 3) / 4;   // 4 waves (rows) per 256-thr block
    spmm_kernel<<<SPMM_BLOCKS, 256, 0, stream>>>(x0h, x1h, row_ptr, pairs);
    spmm_kernel<<<SPMM_BLOCKS, 256, 0, stream>>>(x1h, x2h, row_ptr, pairs);
    spmm_kernel<<<SPMM_BLOCKS, 256, 0, stream>>>(x2h, x3h, row_ptr, pairs);

    loss_fused_kernel<<<BATCH / 4, 256, 0, stream>>>(x1h, x2h, x3h,
        user_table, item_table, user, positive, negative, vnh, posv, oacc);
    gram2_kernel<<<2048, 256, 0, stream>>>(vnh, rowsum);
    lse_kernel<<<(2 * BATCH + 255) / 256, 256, 0, stream>>>(rowsum, posv, oacc);
    final_kernel<<<1, 1, 0, stream>>>(oacc, out);
}

// Round 6
// 359.136 us; speedup vs baseline: 1.2899x; 1.2899x over previous
//
#include <hip/hip_runtime.h>
#include <hip/hip_bf16.h>
#include <math.h>

#define NUM_USERS 60000
#define NUM_ITEMS 40000
#define NUM_NODES (NUM_USERS + NUM_ITEMS)
#define NNZ 2000000
#define DIM 64
#define BATCH 4096
#define TEMP_INV 5.0f   // 1/0.2
#define SCAN_BLOCKS ((NUM_NODES + 1023) / 1024)   // 98
#define PAIR_CAP (NNZ + NUM_NODES * 8)

#define HIST_BLOCKS 1954      // 500000 int4 groups / 256
#define CVT_BLOCKS 1563       // 400000 float4 groups / 256

typedef __attribute__((ext_vector_type(8))) __bf16 bf16x8;
typedef __attribute__((ext_vector_type(4))) float f32x4;

__device__ __forceinline__ ushort f2bf(float f) {           // RNE, finite inputs
    uint u = __float_as_uint(f);
    return (ushort)((u + 0x7FFF + ((u >> 16) & 1)) >> 16);
}
__device__ __forceinline__ float bf2f(ushort u) {
    return __uint_as_float((uint)u << 16);
}

// ---- fused: edge-row histogram w/ rank (4 atomics in flight) + table cvt ----

__global__ __launch_bounds__(256) void fused1_kernel(const int* __restrict__ row,
        int* __restrict__ cnt, int* __restrict__ rank, const float* __restrict__ ut,
        const float* __restrict__ it, ushort* __restrict__ x0) {
    int b = blockIdx.x;
    if (b < HIST_BLOCKS) {
        int g = b * 256 + threadIdx.x;
        if (g < NNZ / 4) {
            int4 r = ((const int4*)row)[g];
            int4 k;
            k.x = atomicAdd(&cnt[r.x], 1);   // 4 independent returns in flight
            k.y = atomicAdd(&cnt[r.y], 1);
            k.z = atomicAdd(&cnt[r.z], 1);
            k.w = atomicAdd(&cnt[r.w], 1);
            ((int4*)rank)[g] = k;            // one coalesced 16B store
        }
    } else {
        int g = (b - HIST_BLOCKS) * 256 + threadIdx.x;
        const int total4 = NUM_NODES * DIM / 4;
        if (g < total4) {
            size_t off = (size_t)g * 4;
            const float* src = (off < (size_t)NUM_USERS * DIM)
                                   ? ut + off
                                   : it + (off - (size_t)NUM_USERS * DIM);
            float4 v = *(const float4*)src;
            ushort4 o;
            o.x = f2bf(v.x); o.y = f2bf(v.y); o.z = f2bf(v.z); o.w = f2bf(v.w);
            *(ushort4*)&x0[off] = o;
        }
    }
}

// ---------------- CSR scan (rows padded to multiple of 8) ----------------

__global__ __launch_bounds__(1024) void scan1_kernel(const int* __restrict__ cnt,
        int* __restrict__ ptr, int* __restrict__ bsum, int n) {
    __shared__ int sh[1024];
    int t = threadIdx.x;
    int i = blockIdx.x * 1024 + t;
    int v = (i < n) ? ((cnt[i] + 7) & ~7) : 0;   // padded row length
    sh[t] = v;
    __syncthreads();
    for (int d = 1; d < 1024; d <<= 1) {
        int w = (t >= d) ? sh[t - d] : 0;
        __syncthreads();
        sh[t] += w;
        __syncthreads();
    }
    int incl = sh[t];
    if (i < n) ptr[i] = incl - v;
    if (t == 1023) bsum[blockIdx.x] = incl;
}

__global__ __launch_bounds__(128) void scan2_kernel(const int* __restrict__ bsum,
        int* __restrict__ boffs, int* __restrict__ ptr, int nb, int n) {
    __shared__ int sh[128];
    int t = threadIdx.x;
    int v = (t < nb) ? bsum[t] : 0;
    sh[t] = v;
    __syncthreads();
    for (int d = 1; d < 128; d <<= 1) {
        int w = (t >= d) ? sh[t - d] : 0;
        __syncthreads();
        sh[t] += w;
        __syncthreads();
    }
    if (t < nb) boffs[t] = sh[t] - v;
    if (t == 127) ptr[n] = sh[127];
}

__global__ __launch_bounds__(1024) void scan3_kernel(int* __restrict__ ptr,
        const int* __restrict__ boffs, int n) {
    int i = blockIdx.x * 1024 + threadIdx.x;
    if (i < n) ptr[i] += boffs[blockIdx.x];
}

// ------------- atomic-free scatter (4 edges/thread, stores independent) ------

__global__ __launch_bounds__(256) void scatter_kernel(const int* __restrict__ row,
        const int* __restrict__ col, const float* __restrict__ val,
        const int* __restrict__ ptr, const int* __restrict__ rank,
        int2* __restrict__ pairs) {
    int g = blockIdx.x * 256 + threadIdx.x;
    if (g >= NNZ / 4) return;
    int4 r = ((const int4*)row)[g];
    int4 c = ((const int4*)col)[g];
    float4 v = ((const float4*)val)[g];
    int4 k = ((const int4*)rank)[g];
    int p0 = ptr[r.x] + k.x;
    int p1 = ptr[r.y] + k.y;
    int p2 = ptr[r.z] + k.z;
    int p3 = ptr[r.w] + k.w;
    pairs[p0] = make_int2(c.x, __float_as_int(v.x));
    pairs[p1] = make_int2(c.y, __float_as_int(v.y));
    pairs[p2] = make_int2(c.z, __float_as_int(v.z));
    pairs[p3] = make_int2(c.w, __float_as_int(v.w));
}

// ---------------- SpMM: wave per row, lane per dim, bf16 in/out ----------------
// Row length is a multiple of 8; pad slots are (col=0, val=0) from the memset.

__global__ __launch_bounds__(256) void spmm_kernel(const ushort* __restrict__ xin,
        ushort* __restrict__ xout,
        const int* __restrict__ ptr, const int2* __restrict__ pairs) {
    int wid = (blockIdx.x * 256 + threadIdx.x) >> 6;
    int lane = threadIdx.x & 63;
    if (wid >= NUM_NODES) return;
    int s = ptr[wid], e = ptr[wid + 1];
    float a0 = 0.f, a1 = 0.f;
    if (s < e) {
        int2 p = pairs[s + (lane & 7)];          // prefetch first chunk
        for (int j = s; j < e; ) {
            int2 q = p;
            j += 8;
            if (j < e) p = pairs[j + (lane & 7)];  // prefetch next chunk
            #pragma unroll
            for (int k = 0; k < 8; ++k) {
                int c = __shfl(q.x, k);
                float v = __int_as_float(__shfl(q.y, k));
                float xv = bf2f(xin[c * DIM + lane]);
                if (k & 1) a1 = fmaf(v, xv, a1); else a0 = fmaf(v, xv, a0);
            }
        }
    }
    xout[wid * DIM + lane] = f2bf(a0 + a1);
}

// ---------------- fused BPR + reg + normalize (wave per batch elem) ----------

__device__ __forceinline__ float wave_sum(float v) {
    for (int o = 32; o; o >>= 1) v += __shfl_xor(v, o);
    return v;
}

__device__ __forceinline__ float acc3(const ushort* x1, const ushort* x2,
                                      const ushort* x3, int node, int lane) {
    int o = node * DIM + lane;
    return (bf2f(x1[o]) + bf2f(x2[o]) + bf2f(x3[o])) * (1.f / 3.f);
}

__global__ __launch_bounds__(256) void loss_fused_kernel(const ushort* __restrict__ x1,
        const ushort* __restrict__ x2, const ushort* __restrict__ x3,
        const float* __restrict__ ut, const float* __restrict__ it,
        const int* __restrict__ user, const int* __restrict__ pos,
        const int* __restrict__ neg, ushort* __restrict__ vnh,
        float* __restrict__ posv, float* __restrict__ oacc) {
    int lane = threadIdx.x & 63;
    int wib = threadIdx.x >> 6;
    int b = blockIdx.x * 4 + wib;      // 1024 blocks x 4 waves = 4096
    int iu = user[b], ip = pos[b], in_ = neg[b];
    float u = acc3(x1, x2, x3, iu, lane);
    float p = acc3(x1, x2, x3, NUM_USERS + ip, lane);
    float n = acc3(x1, x2, x3, NUM_USERS + in_, lane);
    float dp = wave_sum(u * p);
    float dn = wave_sum(u * n);
    float x = dn - dp;
    float sp = fmaxf(x, 0.f) + log1pf(expf(-fabsf(x)));
    float eu = ut[(size_t)iu * DIM + lane];
    float ep = it[(size_t)ip * DIM + lane];
    float en = it[(size_t)in_ * DIM + lane];
    float r = wave_sum(eu * eu + ep * ep + en * en);
    float un2 = wave_sum(u * u);
    float uinv = 1.f / (sqrtf(un2) + 1e-8f);
    vnh[b * DIM + lane] = f2bf(u * uinv);
    float pn2 = wave_sum(p * p);
    float pinv = 1.f / (sqrtf(pn2) + 1e-8f);
    vnh[(BATCH + b) * DIM + lane] = f2bf(p * pinv);
    __shared__ float lsp[4], lrg[4];
    if (lane == 0) {
        lsp[wib] = sp;
        lrg[wib] = r;
        posv[b] = un2 * uinv * uinv * TEMP_INV;
        posv[BATCH + b] = pn2 * pinv * pinv * TEMP_INV;
    }
    __syncthreads();
    if (threadIdx.x == 0) {
        atomicAdd(&oacc[0], lsp[0] + lsp[1] + lsp[2] + lsp[3]);
        atomicAdd(&oacc[1], lrg[0] + lrg[1] + lrg[2] + lrg[3]);
    }
}

// ---------------- MFMA gram + fixed-shift sumexp ----------------

__global__ __launch_bounds__(256) void gram2_kernel(const ushort* __restrict__ vnh_,
                                                    float* __restrict__ rowsum) {
    const __bf16* vnh = (const __bf16*)vnh_;
    int b = blockIdx.x;
    int side = b >> 10;
    int itile = (b >> 2) & 255;
    int jgroup = b & 3;
    int wave = threadIdx.x >> 6;
    int lane = threadIdx.x & 63;
    int jsub = jgroup * 4 + wave;            // 0..15
    const __bf16* base = vnh + (size_t)side * BATCH * DIM;
    int i0 = itile * 16;
    int row = lane & 15;
    int koff = (lane >> 4) * 8;
    bf16x8 a0 = *(const bf16x8*)&base[(i0 + row) * DIM + koff];
    bf16x8 a1 = *(const bf16x8*)&base[(i0 + row) * DIM + 32 + koff];
    float rs[4] = {0.f, 0.f, 0.f, 0.f};
    for (int t = 0; t < 16; ++t) {
        int j0 = (jsub + t * 16) * 16;
        bf16x8 b0 = *(const bf16x8*)&base[(j0 + row) * DIM + koff];
        bf16x8 b1 = *(const bf16x8*)&base[(j0 + row) * DIM + 32 + koff];
        f32x4 c = {0.f, 0.f, 0.f, 0.f};
        c = __builtin_amdgcn_mfma_f32_16x16x32_bf16(a0, b0, c, 0, 0, 0);
        c = __builtin_amdgcn_mfma_f32_16x16x32_bf16(a1, b1, c, 0, 0, 0);
        #pragma unroll
        for (int r = 0; r < 4; ++r)
            rs[r] += __expf(TEMP_INV * c[r] - TEMP_INV);   // logit-5 <= 0
    }
    #pragma unroll
    for (int r = 0; r < 4; ++r) {
        rs[r] += __shfl_xor(rs[r], 1);
        rs[r] += __shfl_xor(rs[r], 2);
        rs[r] += __shfl_xor(rs[r], 4);
        rs[r] += __shfl_xor(rs[r], 8);
    }
    if ((lane & 15) == 0) {
        #pragma unroll
        for (int r = 0; r < 4; ++r)
            atomicAdd(&rowsum[side * BATCH + i0 + (lane >> 4) * 4 + r], rs[r]);
    }
}

__global__ __launch_bounds__(256) void lse_kernel(const float* __restrict__ rowsum,
        const float* __restrict__ posv, float* __restrict__ oacc) {
    int idx = blockIdx.x * 256 + threadIdx.x;
    float c = 0.f;
    if (idx < 2 * BATCH) {
        float s = rowsum[idx];
        c = TEMP_INV + logf(s) - posv[idx];
    }
    c = wave_sum(c);
    __shared__ float l[4];
    int lane = threadIdx.x & 63, w = threadIdx.x >> 6;
    if (lane == 0) l[w] = c;
    __syncthreads();
    if (threadIdx.x == 0) atomicAdd(&oacc[2], l[0] + l[1] + l[2] + l[3]);
}

__global__ void final_kernel(const float* __restrict__ oacc, float* __restrict__ out) {
    out[0] = oacc[0] * (1.f / BATCH);
    out[1] = oacc[1] * (1e-4f * 0.5f / BATCH);
    out[2] = oacc[2] * (0.1f / BATCH);
}

// ---------------- launch ----------------

extern "C" void kernel_launch(void* const* d_in, const int* in_sizes, int n_in,
                              void* d_out, int out_size, void* d_ws, size_t ws_size,
                              hipStream_t stream) {
    const float* user_table = (const float*)d_in[0];
    const float* item_table = (const float*)d_in[1];
    const float* edge_val   = (const float*)d_in[2];
    const int*   user       = (const int*)d_in[3];
    const int*   positive   = (const int*)d_in[4];
    const int*   negative   = (const int*)d_in[5];
    const int*   edge_row   = (const int*)d_in[6];
    const int*   edge_col   = (const int*)d_in[7];
    float* out = (float*)d_out;

    char* w = (char*)d_ws;
    auto alloc = [&](size_t bytes) {
        char* p = w;
        w += (bytes + 255) & ~(size_t)255;
        return p;
    };
    int*    row_ptr = (int*)alloc((NUM_NODES + 1) * sizeof(int));
    int*    cnt     = (int*)alloc(NUM_NODES * sizeof(int));
    int*    rank    = (int*)alloc((size_t)NNZ * sizeof(int));
    int*    bsum    = (int*)alloc(SCAN_BLOCKS * sizeof(int));
    int*    boffs   = (int*)alloc(SCAN_BLOCKS * sizeof(int));
    int2*   pairs   = (int2*)alloc((size_t)PAIR_CAP * sizeof(int2));
    ushort* x0h     = (ushort*)alloc((size_t)NUM_NODES * DIM * sizeof(ushort));
    ushort* x1h     = (ushort*)alloc((size_t)NUM_NODES * DIM * sizeof(ushort));
    ushort* x2h     = (ushort*)alloc((size_t)NUM_NODES * DIM * sizeof(ushort));
    ushort* x3h     = (ushort*)alloc((size_t)NUM_NODES * DIM * sizeof(ushort));
    ushort* vnh     = (ushort*)alloc((size_t)2 * BATCH * DIM * sizeof(ushort));
    float*  posv    = (float*)alloc(2 * BATCH * sizeof(float));
    float*  rowsum  = (float*)alloc(2 * BATCH * sizeof(float));
    float*  oacc    = (float*)alloc(4 * sizeof(float));

    hipMemsetAsync(cnt, 0, NUM_NODES * sizeof(int), stream);
    hipMemsetAsync(oacc, 0, 4 * sizeof(float), stream);
    hipMemsetAsync(rowsum, 0, 2 * BATCH * sizeof(float), stream);
    hipMemsetAsync(pairs, 0, (size_t)PAIR_CAP * sizeof(int2), stream);

    fused1_kernel<<<HIST_BLOCKS + CVT_BLOCKS, 256, 0, stream>>>(
        edge_row, cnt, rank, user_table, item_table, x0h);
    scan1_kernel<<<SCAN_BLOCKS, 1024, 0, stream>>>(cnt, row_ptr, bsum, NUM_NODES);
    scan2_kernel<<<1, 128, 0, stream>>>(bsum, boffs, row_ptr, SCAN_BLOCKS, NUM_NODES);
    scan3_kernel<<<SCAN_BLOCKS, 1024, 0, stream>>>(row_ptr, boffs, NUM_NODES);
    scatter_kernel<<<(NNZ / 4 + 255) / 256, 256, 0, stream>>>(
        edge_row, edge_col, edge_val, row_ptr, rank, pairs);

    const int SPMM_BLOCKS = (NUM_NODES + 3) / 4;   // 4 waves (rows) per 256-thr block
    spmm_kernel<<<SPMM_BLOCKS, 256, 0, stream>>>(x0h, x1h, row_ptr, pairs);
    spmm_kernel<<<SPMM_BLOCKS, 256, 0, stream>>>(x1h, x2h, row_ptr, pairs);
    spmm_kernel<<<SPMM_BLOCKS, 256, 0, stream>>>(x2h, x3h, row_ptr, pairs);

    loss_fused_kernel<<<BATCH / 4, 256, 0, stream>>>(x1h, x2h, x3h,
        user_table, item_table, user, positive, negative, vnh, posv, oacc);
    gram2_kernel<<<2048, 256, 0, stream>>>(vnh, rowsum);
    lse_kernel<<<(2 * BATCH + 255) / 256, 256, 0, stream>>>(rowsum, posv, oacc);
    final_kernel<<<1, 1, 0, stream>>>(oacc, out);
}

// Round 7
// 324.649 us; speedup vs baseline: 1.4269x; 1.1062x over previous
//
#include <hip/hip_runtime.h>
#include <hip/hip_bf16.h>
#include <math.h>

#define NUM_USERS 60000
#define NUM_ITEMS 40000
#define NUM_NODES (NUM_USERS + NUM_ITEMS)
#define NNZ 2000000
#define DIM 64
#define BATCH 4096
#define TEMP_INV 5.0f   // 1/0.2
#define SCAN_BLOCKS ((NUM_NODES + 1023) / 1024)   // 98
#define PAIR_CAP (NNZ + NUM_NODES * 8)

#define HIST_BLOCKS 1954      // 500000 int4 groups / 256
#define CVT_BLOCKS 1563       // 400000 float4 groups / 256

typedef __attribute__((ext_vector_type(8))) __bf16 bf16x8;
typedef __attribute__((ext_vector_type(4))) float f32x4;

__device__ __forceinline__ ushort f2bf(float f) {           // RNE, finite inputs
    uint u = __float_as_uint(f);
    return (ushort)((u + 0x7FFF + ((u >> 16) & 1)) >> 16);
}
__device__ __forceinline__ float bf2f(ushort u) {
    return __uint_as_float((uint)u << 16);
}

// ---- fused: edge-row histogram w/ rank (4 atomics in flight) + table cvt ----

__global__ __launch_bounds__(256) void fused1_kernel(const int* __restrict__ row,
        int* __restrict__ cnt, int* __restrict__ rank, const float* __restrict__ ut,
        const float* __restrict__ it, ushort* __restrict__ x0) {
    int b = blockIdx.x;
    if (b < HIST_BLOCKS) {
        int g = b * 256 + threadIdx.x;
        if (g < NNZ / 4) {
            int4 r = ((const int4*)row)[g];
            int4 k;
            k.x = atomicAdd(&cnt[r.x], 1);   // 4 independent returns in flight
            k.y = atomicAdd(&cnt[r.y], 1);
            k.z = atomicAdd(&cnt[r.z], 1);
            k.w = atomicAdd(&cnt[r.w], 1);
            ((int4*)rank)[g] = k;            // one coalesced 16B store
        }
    } else {
        int g = (b - HIST_BLOCKS) * 256 + threadIdx.x;
        const int total4 = NUM_NODES * DIM / 4;
        if (g < total4) {
            size_t off = (size_t)g * 4;
            const float* src = (off < (size_t)NUM_USERS * DIM)
                                   ? ut + off
                                   : it + (off - (size_t)NUM_USERS * DIM);
            float4 v = *(const float4*)src;
            ushort4 o;
            o.x = f2bf(v.x); o.y = f2bf(v.y); o.z = f2bf(v.z); o.w = f2bf(v.w);
            *(ushort4*)&x0[off] = o;
        }
    }
}

// ---------------- CSR scan (rows padded to multiple of 8) ----------------

__global__ __launch_bounds__(1024) void scan1_kernel(const int* __restrict__ cnt,
        int* __restrict__ ptr, int* __restrict__ bsum, int n) {
    __shared__ int sh[1024];
    int t = threadIdx.x;
    int i = blockIdx.x * 1024 + t;
    int v = (i < n) ? ((cnt[i] + 7) & ~7) : 0;   // padded row length
    sh[t] = v;
    __syncthreads();
    for (int d = 1; d < 1024; d <<= 1) {
        int w = (t >= d) ? sh[t - d] : 0;
        __syncthreads();
        sh[t] += w;
        __syncthreads();
    }
    int incl = sh[t];
    if (i < n) ptr[i] = incl - v;
    if (t == 1023) bsum[blockIdx.x] = incl;
}

__global__ __launch_bounds__(128) void scan2_kernel(const int* __restrict__ bsum,
        int* __restrict__ boffs, int* __restrict__ ptr, int nb, int n) {
    __shared__ int sh[128];
    int t = threadIdx.x;
    int v = (t < nb) ? bsum[t] : 0;
    sh[t] = v;
    __syncthreads();
    for (int d = 1; d < 128; d <<= 1) {
        int w = (t >= d) ? sh[t - d] : 0;
        __syncthreads();
        sh[t] += w;
        __syncthreads();
    }
    if (t < nb) boffs[t] = sh[t] - v;
    if (t == 127) ptr[n] = sh[127];
}

__global__ __launch_bounds__(1024) void scan3_kernel(int* __restrict__ ptr,
        const int* __restrict__ boffs, int n) {
    int i = blockIdx.x * 1024 + threadIdx.x;
    if (i < n) ptr[i] += boffs[blockIdx.x];
}

// ------------- atomic-free scatter (4 edges/thread, stores independent) ------

__global__ __launch_bounds__(256) void scatter_kernel(const int* __restrict__ row,
        const int* __restrict__ col, const float* __restrict__ val,
        const int* __restrict__ ptr, const int* __restrict__ rank,
        int2* __restrict__ pairs) {
    int g = blockIdx.x * 256 + threadIdx.x;
    if (g >= NNZ / 4) return;
    int4 r = ((const int4*)row)[g];
    int4 c = ((const int4*)col)[g];
    float4 v = ((const float4*)val)[g];
    int4 k = ((const int4*)rank)[g];
    int p0 = ptr[r.x] + k.x;
    int p1 = ptr[r.y] + k.y;
    int p2 = ptr[r.z] + k.z;
    int p3 = ptr[r.w] + k.w;
    pairs[p0] = make_int2(c.x, __float_as_int(v.x));
    pairs[p1] = make_int2(c.y, __float_as_int(v.y));
    pairs[p2] = make_int2(c.z, __float_as_int(v.z));
    pairs[p3] = make_int2(c.w, __float_as_int(v.w));
}

// ---------------- SpMM: wave per row; 4-edge-wide uint2 gathers ----------------
// lane = eg*16 + dg: eg = edge subgroup (0..3), dg = dim group (dims 4dg..4dg+3).
// One gather instruction covers 4 edges x 128B rows. Pad slots (col=0,val=0).

__global__ __launch_bounds__(256) void spmm_kernel(const ushort* __restrict__ xin,
        ushort* __restrict__ xout,
        const int* __restrict__ ptr, const int2* __restrict__ pairs) {
    int wid = (blockIdx.x * 256 + threadIdx.x) >> 6;
    int lane = threadIdx.x & 63;
    if (wid >= NUM_NODES) return;
    int s = ptr[wid], e = ptr[wid + 1];
    int dg = lane & 15;
    int eg = lane >> 4;
    float a0 = 0.f, a1 = 0.f, a2 = 0.f, a3 = 0.f;
    for (int base = s; base < e; base += 64) {
        int2 p = pairs[base + lane];          // up to 64 pairs, one coalesced load
        int lim = min(64, e - base);          // multiple of 8
        for (int j = 0; j < lim; j += 8) {
            #pragma unroll
            for (int sub = 0; sub < 2; ++sub) {
                int k = j + sub * 4 + eg;
                int c = __shfl(p.x, k);
                float v = __int_as_float(__shfl(p.y, k));
                uint2 q = *(const uint2*)&xin[c * DIM + dg * 4];
                a0 = fmaf(v, bf2f((ushort)(q.x & 0xffff)), a0);
                a1 = fmaf(v, bf2f((ushort)(q.x >> 16)), a1);
                a2 = fmaf(v, bf2f((ushort)(q.y & 0xffff)), a2);
                a3 = fmaf(v, bf2f((ushort)(q.y >> 16)), a3);
            }
        }
    }
    a0 += __shfl_xor(a0, 16); a0 += __shfl_xor(a0, 32);
    a1 += __shfl_xor(a1, 16); a1 += __shfl_xor(a1, 32);
    a2 += __shfl_xor(a2, 16); a2 += __shfl_xor(a2, 32);
    a3 += __shfl_xor(a3, 16); a3 += __shfl_xor(a3, 32);
    if (eg == 0) {
        ushort4 o = make_ushort4(f2bf(a0), f2bf(a1), f2bf(a2), f2bf(a3));
        *(ushort4*)&xout[wid * DIM + dg * 4] = o;
    }
}

// ---------------- fused BPR + reg + normalize (wave per batch elem) ----------

__device__ __forceinline__ float wave_sum(float v) {
    for (int o = 32; o; o >>= 1) v += __shfl_xor(v, o);
    return v;
}

__device__ __forceinline__ float acc3(const ushort* x1, const ushort* x2,
                                      const ushort* x3, int node, int lane) {
    int o = node * DIM + lane;
    return (bf2f(x1[o]) + bf2f(x2[o]) + bf2f(x3[o])) * (1.f / 3.f);
}

__global__ __launch_bounds__(256) void loss_fused_kernel(const ushort* __restrict__ x1,
        const ushort* __restrict__ x2, const ushort* __restrict__ x3,
        const float* __restrict__ ut, const float* __restrict__ it,
        const int* __restrict__ user, const int* __restrict__ pos,
        const int* __restrict__ neg, ushort* __restrict__ vnh,
        float* __restrict__ posv, float* __restrict__ oacc) {
    int lane = threadIdx.x & 63;
    int wib = threadIdx.x >> 6;
    int b = blockIdx.x * 4 + wib;      // 1024 blocks x 4 waves = 4096
    int iu = user[b], ip = pos[b], in_ = neg[b];
    float u = acc3(x1, x2, x3, iu, lane);
    float p = acc3(x1, x2, x3, NUM_USERS + ip, lane);
    float n = acc3(x1, x2, x3, NUM_USERS + in_, lane);
    float dp = wave_sum(u * p);
    float dn = wave_sum(u * n);
    float x = dn - dp;
    float sp = fmaxf(x, 0.f) + log1pf(expf(-fabsf(x)));
    float eu = ut[(size_t)iu * DIM + lane];
    float ep = it[(size_t)ip * DIM + lane];
    float en = it[(size_t)in_ * DIM + lane];
    float r = wave_sum(eu * eu + ep * ep + en * en);
    float un2 = wave_sum(u * u);
    float uinv = 1.f / (sqrtf(un2) + 1e-8f);
    vnh[b * DIM + lane] = f2bf(u * uinv);
    float pn2 = wave_sum(p * p);
    float pinv = 1.f / (sqrtf(pn2) + 1e-8f);
    vnh[(BATCH + b) * DIM + lane] = f2bf(p * pinv);
    __shared__ float lsp[4], lrg[4];
    if (lane == 0) {
        lsp[wib] = sp;
        lrg[wib] = r;
        posv[b] = un2 * uinv * uinv * TEMP_INV;
        posv[BATCH + b] = pn2 * pinv * pinv * TEMP_INV;
    }
    __syncthreads();
    if (threadIdx.x == 0) {
        atomicAdd(&oacc[0], lsp[0] + lsp[1] + lsp[2] + lsp[3]);
        atomicAdd(&oacc[1], lrg[0] + lrg[1] + lrg[2] + lrg[3]);
    }
}

// ---------------- MFMA gram + fixed-shift sumexp ----------------

__global__ __launch_bounds__(256) void gram2_kernel(const ushort* __restrict__ vnh_,
                                                    float* __restrict__ rowsum) {
    const __bf16* vnh = (const __bf16*)vnh_;
    int b = blockIdx.x;
    int side = b >> 10;
    int itile = (b >> 2) & 255;
    int jgroup = b & 3;
    int wave = threadIdx.x >> 6;
    int lane = threadIdx.x & 63;
    int jsub = jgroup * 4 + wave;            // 0..15
    const __bf16* base = vnh + (size_t)side * BATCH * DIM;
    int i0 = itile * 16;
    int row = lane & 15;
    int koff = (lane >> 4) * 8;
    bf16x8 a0 = *(const bf16x8*)&base[(i0 + row) * DIM + koff];
    bf16x8 a1 = *(const bf16x8*)&base[(i0 + row) * DIM + 32 + koff];
    float rs[4] = {0.f, 0.f, 0.f, 0.f};
    for (int t = 0; t < 16; ++t) {
        int j0 = (jsub + t * 16) * 16;
        bf16x8 b0 = *(const bf16x8*)&base[(j0 + row) * DIM + koff];
        bf16x8 b1 = *(const bf16x8*)&base[(j0 + row) * DIM + 32 + koff];
        f32x4 c = {0.f, 0.f, 0.f, 0.f};
        c = __builtin_amdgcn_mfma_f32_16x16x32_bf16(a0, b0, c, 0, 0, 0);
        c = __builtin_amdgcn_mfma_f32_16x16x32_bf16(a1, b1, c, 0, 0, 0);
        #pragma unroll
        for (int r = 0; r < 4; ++r)
            rs[r] += __expf(TEMP_INV * c[r] - TEMP_INV);   // logit-5 <= 0
    }
    #pragma unroll
    for (int r = 0; r < 4; ++r) {
        rs[r] += __shfl_xor(rs[r], 1);
        rs[r] += __shfl_xor(rs[r], 2);
        rs[r] += __shfl_xor(rs[r], 4);
        rs[r] += __shfl_xor(rs[r], 8);
    }
    if ((lane & 15) == 0) {
        #pragma unroll
        for (int r = 0; r < 4; ++r)
            atomicAdd(&rowsum[side * BATCH + i0 + (lane >> 4) * 4 + r], rs[r]);
    }
}

__global__ __launch_bounds__(256) void lse_kernel(const float* __restrict__ rowsum,
        const float* __restrict__ posv, float* __restrict__ oacc) {
    int idx = blockIdx.x * 256 + threadIdx.x;
    float c = 0.f;
    if (idx < 2 * BATCH) {
        float s = rowsum[idx];
        c = TEMP_INV + logf(s) - posv[idx];
    }
    c = wave_sum(c);
    __shared__ float l[4];
    int lane = threadIdx.x & 63, w = threadIdx.x >> 6;
    if (lane == 0) l[w] = c;
    __syncthreads();
    if (threadIdx.x == 0) atomicAdd(&oacc[2], l[0] + l[1] + l[2] + l[3]);
}

__global__ void final_kernel(const float* __restrict__ oacc, float* __restrict__ out) {
    out[0] = oacc[0] * (1.f / BATCH);
    out[1] = oacc[1] * (1e-4f * 0.5f / BATCH);
    out[2] = oacc[2] * (0.1f / BATCH);
}

// ---------------- launch ----------------

extern "C" void kernel_launch(void* const* d_in, const int* in_sizes, int n_in,
                              void* d_out, int out_size, void* d_ws, size_t ws_size,
                              hipStream_t stream) {
    const float* user_table = (const float*)d_in[0];
    const float* item_table = (const float*)d_in[1];
    const float* edge_val   = (const float*)d_in[2];
    const int*   user       = (const int*)d_in[3];
    const int*   positive   = (const int*)d_in[4];
    const int*   negative   = (const int*)d_in[5];
    const int*   edge_row   = (const int*)d_in[6];
    const int*   edge_col   = (const int*)d_in[7];
    float* out = (float*)d_out;

    char* w = (char*)d_ws;
    auto alloc = [&](size_t bytes) {
        char* p = w;
        w += (bytes + 255) & ~(size_t)255;
        return p;
    };
    int*    row_ptr = (int*)alloc((NUM_NODES + 1) * sizeof(int));
    int*    cnt     = (int*)alloc(NUM_NODES * sizeof(int));
    int*    rank    = (int*)alloc((size_t)NNZ * sizeof(int));
    int*    bsum    = (int*)alloc(SCAN_BLOCKS * sizeof(int));
    int*    boffs   = (int*)alloc(SCAN_BLOCKS * sizeof(int));
    int2*   pairs   = (int2*)alloc((size_t)PAIR_CAP * sizeof(int2));
    ushort* x0h     = (ushort*)alloc((size_t)NUM_NODES * DIM * sizeof(ushort));
    ushort* x1h     = (ushort*)alloc((size_t)NUM_NODES * DIM * sizeof(ushort));
    ushort* x2h     = (ushort*)alloc((size_t)NUM_NODES * DIM * sizeof(ushort));
    ushort* x3h     = (ushort*)alloc((size_t)NUM_NODES * DIM * sizeof(ushort));
    ushort* vnh     = (ushort*)alloc((size_t)2 * BATCH * DIM * sizeof(ushort));
    float*  posv    = (float*)alloc(2 * BATCH * sizeof(float));
    float*  rowsum  = (float*)alloc(2 * BATCH * sizeof(float));
    float*  oacc    = (float*)alloc(4 * sizeof(float));

    hipMemsetAsync(cnt, 0, NUM_NODES * sizeof(int), stream);
    hipMemsetAsync(oacc, 0, 4 * sizeof(float), stream);
    hipMemsetAsync(rowsum, 0, 2 * BATCH * sizeof(float), stream);
    hipMemsetAsync(pairs, 0, (size_t)PAIR_CAP * sizeof(int2), stream);

    fused1_kernel<<<HIST_BLOCKS + CVT_BLOCKS, 256, 0, stream>>>(
        edge_row, cnt, rank, user_table, item_table, x0h);
    scan1_kernel<<<SCAN_BLOCKS, 1024, 0, stream>>>(cnt, row_ptr, bsum, NUM_NODES);
    scan2_kernel<<<1, 128, 0, stream>>>(bsum, boffs, row_ptr, SCAN_BLOCKS, NUM_NODES);
    scan3_kernel<<<SCAN_BLOCKS, 1024, 0, stream>>>(row_ptr, boffs, NUM_NODES);
    scatter_kernel<<<(NNZ / 4 + 255) / 256, 256, 0, stream>>>(
        edge_row, edge_col, edge_val, row_ptr, rank, pairs);

    const int SPMM_BLOCKS = (NUM_NODES + 3) / 4;   // 4 waves (rows) per 256-thr block
    spmm_kernel<<<SPMM_BLOCKS, 256, 0, stream>>>(x0h, x1h, row_ptr, pairs);
    spmm_kernel<<<SPMM_BLOCKS, 256, 0, stream>>>(x1h, x2h, row_ptr, pairs);
    spmm_kernel<<<SPMM_BLOCKS, 256, 0, stream>>>(x2h, x3h, row_ptr, pairs);

    loss_fused_kernel<<<BATCH / 4, 256, 0, stream>>>(x1h, x2h, x3h,
        user_table, item_table, user, positive, negative, vnh, posv, oacc);
    gram2_kernel<<<2048, 256, 0, stream>>>(vnh, rowsum);
    lse_kernel<<<(2 * BATCH + 255) / 256, 256, 0, stream>>>(rowsum, posv, oacc);
    final_kernel<<<1, 1, 0, stream>>>(oacc, out);
}